// Round 1
// baseline (1131.182 us; speedup 1.0000x reference)
//
#include <hip/hip_runtime.h>
#include <math.h>

typedef _Float16 f16x2 __attribute__((ext_vector_type(2)));
typedef _Float16 f16x8 __attribute__((ext_vector_type(8)));

__device__ __forceinline__ float fdot2(f16x2 a, f16x2 b, float c) {
#if defined(__has_builtin)
#if __has_builtin(__builtin_amdgcn_fdot2)
  return __builtin_amdgcn_fdot2(a, b, c, false);
#else
  return c + (float)a[0] * (float)b[0] + (float)a[1] * (float)b[1];
#endif
#else
  return c + (float)a[0] * (float)b[0] + (float)a[1] * (float)b[1];
#endif
}

__device__ __forceinline__ float sigmoidf_(float v) {
  return 1.0f / (1.0f + __expf(-v));
}
__device__ __forceinline__ float tanhf_(float v) {
  v = fminf(fmaxf(v, -15.f), 15.f);
  float e = __expf(2.f * v);
  return (e - 1.f) / (e + 1.f);
}

#define WSTR 196  // weight LDS row stride in f16x2 units (192 + pad4, keeps b128 alignment)
#define XSTR 65   // data LDS row stride (64 + 1 pad -> conflict-free transposed writes)

// ---------------- CSR build ----------------
__global__ __launch_bounds__(256) void hist_kernel(const int* __restrict__ dst,
                                                   int* __restrict__ deg, int E) {
  int e = blockIdx.x * 256 + threadIdx.x;
  if (e < E) atomicAdd(&deg[dst[e]], 1);
}

__global__ __launch_bounds__(256) void reduce_kernel(const int* __restrict__ deg,
                                                     int* __restrict__ bsum, int N) {
  __shared__ int s[256];
  int t = threadIdx.x;
  int i = blockIdx.x * 256 + t;
  s[t] = (i < N) ? deg[i] : 0;
  __syncthreads();
  for (int off = 128; off > 0; off >>= 1) {
    if (t < off) s[t] += s[t + off];
    __syncthreads();
  }
  if (t == 0) bsum[blockIdx.x] = s[0];
}

__global__ __launch_bounds__(512) void scan_bsums_kernel(int* __restrict__ bsum, int nb,
                                                         int* __restrict__ offs, int N, int E) {
  __shared__ int s[512];
  int t = threadIdx.x;
  int v = (t < nb) ? bsum[t] : 0;
  s[t] = v;
  __syncthreads();
  for (int off = 1; off < 512; off <<= 1) {
    int add = (t >= off) ? s[t - off] : 0;
    __syncthreads();
    s[t] += add;
    __syncthreads();
  }
  if (t < nb) bsum[t] = s[t] - v;  // exclusive
  if (t == 0) offs[N] = E;
}

__global__ __launch_bounds__(256) void scan_block_kernel(const int* __restrict__ deg,
                                                         const int* __restrict__ bsum,
                                                         int* __restrict__ offs, int N) {
  __shared__ int s[256];
  int t = threadIdx.x;
  int i = blockIdx.x * 256 + t;
  int v = (i < N) ? deg[i] : 0;
  s[t] = v;
  __syncthreads();
  for (int off = 1; off < 256; off <<= 1) {
    int add = (t >= off) ? s[t - off] : 0;
    __syncthreads();
    s[t] += add;
    __syncthreads();
  }
  if (i < N) offs[i] = bsum[blockIdx.x] + s[t] - v;
}

__global__ __launch_bounds__(256) void fill_kernel(const int* __restrict__ src,
                                                   const int* __restrict__ dst,
                                                   int* __restrict__ cursor,
                                                   int* __restrict__ srcs, int E) {
  int e = blockIdx.x * 256 + threadIdx.x;
  if (e < E) {
    int d = dst[e];
    int pos = atomicAdd(&cursor[d], 1);
    srcs[pos] = src[e];
  }
}

// ---------------- conv: m = x @ W  (W is [k][j] row-major) ----------------
__global__ __launch_bounds__(256) void conv_kernel(const float* __restrict__ x,
                                                   const float* __restrict__ W,
                                                   float* __restrict__ m, int N, int numTiles) {
  __shared__ f16x2 sW[32 * 68];
  __shared__ f16x2 sX[32 * XSTR];
  const int t = threadIdx.x;
  {
    int j = t & 63, k2b = t >> 6;
    for (int k2 = k2b; k2 < 32; k2 += 4) {
      float a = W[(2 * k2) * 64 + j];
      float b = W[(2 * k2 + 1) * 64 + j];
      f16x2 w;
      w[0] = (_Float16)a;
      w[1] = (_Float16)b;
      sW[k2 * 68 + j] = w;
    }
  }
  const int dq = t & 15, nq = t >> 4;
  const int d0 = dq * 4;
  for (int tile = blockIdx.x; tile < numTiles; tile += gridDim.x) {
    const int nbase = tile * 64;
    __syncthreads();
    {
      int k2s = t & 31, ns = t >> 5;
      for (int nn = ns; nn < 64; nn += 8) {
        int node = nbase + nn;
        float2 xv = {0.f, 0.f};
        if (node < N) xv = *(const float2*)(x + (size_t)node * 64 + 2 * k2s);
        f16x2 h;
        h[0] = (_Float16)xv.x;
        h[1] = (_Float16)xv.y;
        sX[k2s * XSTR + nn] = h;
      }
    }
    __syncthreads();
    float acc[4][4];
#pragma unroll
    for (int ni = 0; ni < 4; ++ni)
#pragma unroll
      for (int di = 0; di < 4; ++di) acc[ni][di] = 0.f;
    for (int k2 = 0; k2 < 32; ++k2) {
      f16x8 w8 = *(const f16x8*)(sW + k2 * 68 + d0);
#pragma unroll
      for (int ni = 0; ni < 4; ++ni) {
        f16x2 a = sX[k2 * XSTR + nq * 4 + ni];
#pragma unroll
        for (int di = 0; di < 4; ++di) {
          f16x2 w;
          w[0] = w8[2 * di];
          w[1] = w8[2 * di + 1];
          acc[ni][di] = fdot2(a, w, acc[ni][di]);
        }
      }
    }
#pragma unroll
    for (int ni = 0; ni < 4; ++ni) {
      int node = nbase + nq * 4 + ni;
      if (node < N) {
        float4 v;
        v.x = acc[ni][0];
        v.y = acc[ni][1];
        v.z = acc[ni][2];
        v.w = acc[ni][3];
        *(float4*)(m + (size_t)node * 64 + d0) = v;
      }
    }
  }
}

// ---------------- aggregate: agg[v] = sum_{e in CSR[v]} m[srcs[e]] ----------------
__global__ __launch_bounds__(256) void agg_kernel(const float* __restrict__ m,
                                                  const int* __restrict__ offs,
                                                  const int* __restrict__ srcs,
                                                  float* __restrict__ agg, int N) {
  int wave = threadIdx.x >> 6, lane = threadIdx.x & 63;
  int v = blockIdx.x * 4 + wave;
  if (v >= N) return;
  int beg = offs[v], end = offs[v + 1];
  float acc = 0.f;
  int e = beg;
  for (; e + 4 <= end; e += 4) {
    int s0 = srcs[e], s1 = srcs[e + 1], s2 = srcs[e + 2], s3 = srcs[e + 3];
    float a0 = m[(size_t)s0 * 64 + lane];
    float a1 = m[(size_t)s1 * 64 + lane];
    float a2 = m[(size_t)s2 * 64 + lane];
    float a3 = m[(size_t)s3 * 64 + lane];
    acc += a0 + a1 + a2 + a3;
  }
  for (; e < end; ++e) acc += m[(size_t)srcs[e] * 64 + lane];
  agg[(size_t)v * 64 + lane] = acc;
}

// ---------------- fused GRU: x = GRUCell(agg, x) ----------------
__global__ __launch_bounds__(256) void gru_kernel(const float* __restrict__ agg,
                                                  float* __restrict__ x,
                                                  const float* __restrict__ w_ih,
                                                  const float* __restrict__ w_hh,
                                                  const float* __restrict__ b_ih,
                                                  const float* __restrict__ b_hh,
                                                  int N, int numTiles) {
  __shared__ f16x2 sWih[32 * WSTR];
  __shared__ f16x2 sWhh[32 * WSTR];
  __shared__ f16x2 sA[16 * XSTR];
  __shared__ f16x2 sH[16 * XSTR];
  const int t = threadIdx.x;
  {
    const int k2 = t & 31, jb = t >> 5;
    for (int j = jb; j < 192; j += 8) {
      float2 wi = *(const float2*)(w_ih + j * 64 + 2 * k2);
      float2 wh = *(const float2*)(w_hh + j * 64 + 2 * k2);
      f16x2 a, b;
      a[0] = (_Float16)wi.x;
      a[1] = (_Float16)wi.y;
      b[0] = (_Float16)wh.x;
      b[1] = (_Float16)wh.y;
      sWih[k2 * WSTR + j] = a;
      sWhh[k2 * WSTR + j] = b;
    }
  }
  const int dq = t & 15, nq = t >> 4;
  const int d0 = dq * 4;
  for (int tile = blockIdx.x; tile < numTiles; tile += gridDim.x) {
    const int nbase = tile * 64;
    float acc[6][4][4];
#pragma unroll
    for (int gg = 0; gg < 6; ++gg)
#pragma unroll
      for (int ni = 0; ni < 4; ++ni)
#pragma unroll
        for (int di = 0; di < 4; ++di) acc[gg][ni][di] = 0.f;
#pragma unroll
    for (int half = 0; half < 2; ++half) {
      __syncthreads();
      {
        const int k2s = t & 15, ns = t >> 4;
        for (int nn = ns; nn < 64; nn += 16) {
          const int node = nbase + nn;
          float2 av = {0.f, 0.f}, hv = {0.f, 0.f};
          if (node < N) {
            av = *(const float2*)(agg + (size_t)node * 64 + half * 32 + 2 * k2s);
            hv = *(const float2*)(x + (size_t)node * 64 + half * 32 + 2 * k2s);
          }
          f16x2 a, h;
          a[0] = (_Float16)av.x;
          a[1] = (_Float16)av.y;
          h[0] = (_Float16)hv.x;
          h[1] = (_Float16)hv.y;
          sA[k2s * XSTR + nn] = a;
          sH[k2s * XSTR + nn] = h;
        }
      }
      __syncthreads();
      for (int k2 = 0; k2 < 16; ++k2) {
        const int kk = half * 16 + k2;
        f16x8 wir = *(const f16x8*)(sWih + kk * WSTR + 0 + d0);
        f16x8 wiz = *(const f16x8*)(sWih + kk * WSTR + 64 + d0);
        f16x8 win = *(const f16x8*)(sWih + kk * WSTR + 128 + d0);
        f16x8 whr = *(const f16x8*)(sWhh + kk * WSTR + 0 + d0);
        f16x8 whz = *(const f16x8*)(sWhh + kk * WSTR + 64 + d0);
        f16x8 whn = *(const f16x8*)(sWhh + kk * WSTR + 128 + d0);
#pragma unroll
        for (int ni = 0; ni < 4; ++ni) {
          f16x2 a = sA[k2 * XSTR + nq * 4 + ni];
          f16x2 h = sH[k2 * XSTR + nq * 4 + ni];
#pragma unroll
          for (int di = 0; di < 4; ++di) {
            f16x2 w;
            w[0] = wir[2 * di]; w[1] = wir[2 * di + 1];
            acc[0][ni][di] = fdot2(a, w, acc[0][ni][di]);
            w[0] = wiz[2 * di]; w[1] = wiz[2 * di + 1];
            acc[1][ni][di] = fdot2(a, w, acc[1][ni][di]);
            w[0] = win[2 * di]; w[1] = win[2 * di + 1];
            acc[2][ni][di] = fdot2(a, w, acc[2][ni][di]);
            w[0] = whr[2 * di]; w[1] = whr[2 * di + 1];
            acc[3][ni][di] = fdot2(h, w, acc[3][ni][di]);
            w[0] = whz[2 * di]; w[1] = whz[2 * di + 1];
            acc[4][ni][di] = fdot2(h, w, acc[4][ni][di]);
            w[0] = whn[2 * di]; w[1] = whn[2 * di + 1];
            acc[5][ni][di] = fdot2(h, w, acc[5][ni][di]);
          }
        }
      }
    }
#pragma unroll
    for (int ni = 0; ni < 4; ++ni) {
      int node = nbase + nq * 4 + ni;
      if (node < N) {
        float4 hold = *(const float4*)(x + (size_t)node * 64 + d0);
        float ho[4] = {hold.x, hold.y, hold.z, hold.w};
        float out[4];
#pragma unroll
        for (int di = 0; di < 4; ++di) {
          int d = d0 + di;
          float ir = acc[0][ni][di] + b_ih[d];
          float iz = acc[1][ni][di] + b_ih[64 + d];
          float in_ = acc[2][ni][di] + b_ih[128 + d];
          float hr = acc[3][ni][di] + b_hh[d];
          float hz = acc[4][ni][di] + b_hh[64 + d];
          float hn = acc[5][ni][di] + b_hh[128 + d];
          float r = sigmoidf_(ir + hr);
          float z = sigmoidf_(iz + hz);
          float nn = tanhf_(in_ + r * hn);
          out[di] = (1.f - z) * nn + z * ho[di];
        }
        float4 v;
        v.x = out[0]; v.y = out[1]; v.z = out[2]; v.w = out[3];
        *(float4*)(x + (size_t)node * 64 + d0) = v;
      }
    }
  }
}

// ---------------- pooling (batch is sorted -> run-length + few atomics) ----------------
__global__ __launch_bounds__(256) void pool_kernel(const float* __restrict__ x,
                                                   const int* __restrict__ batch,
                                                   float* __restrict__ g, int N) {
  int wave = threadIdx.x >> 6, lane = threadIdx.x & 63;
  int n0 = blockIdx.x * 64 + wave * 16;
  if (n0 >= N) return;
  int end = n0 + 16;
  if (end > N) end = N;
  int cur = batch[n0];
  float acc = 0.f;
  for (int n = n0; n < end; ++n) {
    int b = batch[n];
    if (b != cur) {
      atomicAdd(&g[(size_t)cur * 64 + lane], acc);
      acc = 0.f;
      cur = b;
    }
    acc += x[(size_t)n * 64 + lane];
  }
  atomicAdd(&g[(size_t)cur * 64 + lane], acc);
}

// ---------------- final MLP ----------------
__device__ __forceinline__ float eluf_(float v) { return v > 0.f ? v : (__expf(v) - 1.f); }

__global__ __launch_bounds__(256) void mlp_kernel(const float* __restrict__ g,
                                                  const float* __restrict__ w1,
                                                  const float* __restrict__ b1,
                                                  const float* __restrict__ w2,
                                                  const float* __restrict__ b2,
                                                  const float* __restrict__ w3,
                                                  const float* __restrict__ b3,
                                                  float* __restrict__ out, int G) {
  __shared__ float sG[64 * 64];
  __shared__ float sH1[64 * 32];
  __shared__ float sH2[64 * 16];
  int t = threadIdx.x;
  for (int i = t; i < G * 64; i += 256) sG[i] = g[i];
  __syncthreads();
  for (int o = t; o < G * 32; o += 256) {
    int gi = o >> 5, i = o & 31;
    float a = b1[i];
    for (int k = 0; k < 64; ++k) a += sG[gi * 64 + k] * w1[i * 64 + k];
    sH1[gi * 32 + i] = eluf_(a);
  }
  __syncthreads();
  for (int o = t; o < G * 16; o += 256) {
    int gi = o >> 4, i = o & 15;
    float a = b2[i];
    for (int k = 0; k < 32; ++k) a += sH1[gi * 32 + k] * w2[i * 32 + k];
    sH2[gi * 16 + i] = eluf_(a);
  }
  __syncthreads();
  for (int o = t; o < G; o += 256) {
    float a = b3[0];
    for (int k = 0; k < 16; ++k) a += sH2[o * 16 + k] * w3[k];
    out[o] = a;
  }
}

extern "C" void kernel_launch(void* const* d_in, const int* in_sizes, int n_in,
                              void* d_out, int out_size, void* d_ws, size_t ws_size,
                              hipStream_t stream) {
  const float* conv_w = (const float*)d_in[0];
  const float* w_ih = (const float*)d_in[1];
  const float* w_hh = (const float*)d_in[2];
  const float* b_ih = (const float*)d_in[3];
  const float* b_hh = (const float*)d_in[4];
  const float* fc1_w = (const float*)d_in[5];
  const float* fc1_b = (const float*)d_in[6];
  const float* fc2_w = (const float*)d_in[7];
  const float* fc2_b = (const float*)d_in[8];
  const float* fc3_w = (const float*)d_in[9];
  const float* fc3_b = (const float*)d_in[10];
  const int* ei = (const int*)d_in[11];
  const int* batch = (const int*)d_in[12];
  const int N = in_sizes[12];
  const int E = in_sizes[11] / 2;
  const int G = out_size;
  const int* src = ei;
  const int* dst = ei + E;

  char* ws = (char*)d_ws;
  size_t off = 0;
  auto alloc = [&](size_t bytes) -> void* {
    void* p = ws + off;
    off += (bytes + 255) & ~(size_t)255;
    return p;
  };
  float* x = (float*)alloc((size_t)N * 64 * 4);
  float* m = (float*)alloc((size_t)N * 64 * 4);
  float* agg = (float*)alloc((size_t)N * 64 * 4);
  float* gbuf = (float*)alloc((size_t)G * 64 * 4);
  int* offs = (int*)alloc((size_t)(N + 1) * 4);
  int* cursor = (int*)alloc((size_t)N * 4);
  int* srcs = (int*)alloc((size_t)E * 4);
  int* bsum = (int*)alloc(512 * 4);

  const int EB = (E + 255) / 256;
  const int NB = (N + 255) / 256;
  const int tiles = (N + 63) / 64;

  // CSR build (by dst)
  hipMemsetAsync(cursor, 0, (size_t)N * 4, stream);
  hist_kernel<<<EB, 256, 0, stream>>>(dst, cursor, E);
  reduce_kernel<<<NB, 256, 0, stream>>>(cursor, bsum, N);
  scan_bsums_kernel<<<1, 512, 0, stream>>>(bsum, NB, offs, N, E);
  scan_block_kernel<<<NB, 256, 0, stream>>>(cursor, bsum, offs, N);
  hipMemcpyAsync(cursor, offs, (size_t)N * 4, hipMemcpyDeviceToDevice, stream);
  fill_kernel<<<EB, 256, 0, stream>>>(src, dst, cursor, srcs, E);

  // layer 0: x=0 -> m=0 -> agg=0; just GRU on zeros
  hipMemsetAsync(x, 0, (size_t)N * 64 * 4, stream);
  hipMemsetAsync(agg, 0, (size_t)N * 64 * 4, stream);
  gru_kernel<<<1024, 256, 0, stream>>>(agg, x, w_ih, w_hh, b_ih, b_hh, N, tiles);

  for (int l = 1; l < 5; ++l) {
    conv_kernel<<<1024, 256, 0, stream>>>(x, conv_w + (size_t)l * 64 * 64, m, N, tiles);
    agg_kernel<<<(N + 3) / 4, 256, 0, stream>>>(m, offs, srcs, agg, N);
    gru_kernel<<<1024, 256, 0, stream>>>(agg, x, w_ih + (size_t)l * 192 * 64,
                                         w_hh + (size_t)l * 192 * 64, b_ih + (size_t)l * 192,
                                         b_hh + (size_t)l * 192, N, tiles);
  }

  hipMemsetAsync(gbuf, 0, (size_t)G * 64 * 4, stream);
  pool_kernel<<<(N + 63) / 64, 256, 0, stream>>>(x, batch, gbuf, N);
  mlp_kernel<<<1, 256, 0, stream>>>(gbuf, fc1_w, fc1_b, fc2_w, fc2_b, fc3_w, fc3_b,
                                    (float*)d_out, G);
}